// Round 1
// baseline (777.562 us; speedup 1.0000x reference)
//
#include <hip/hip_runtime.h>

typedef __attribute__((ext_vector_type(8))) short s8_t;   // 8 bf16 (4 VGPRs) MFMA frag
typedef __attribute__((ext_vector_type(4))) float f4_t;   // MFMA accumulator

#define NBATCH 256
#define NCH    128
#define NT     4096
#define NF     64
#define TT     128            // time tile
#define NIT    (NT / TT)      // 32
#define LDSK   (TT + 8)       // padded LDS row stride (bf16 elems) -> 2-way max bank aliasing
#define CHEB_D 28

static __device__ __forceinline__ unsigned short f32_bf16(float f) {
    unsigned int u = __float_as_uint(f);
    return (unsigned short)((u + 0x7FFFu + ((u >> 16) & 1u)) >> 16);  // RNE
}
static __device__ __forceinline__ float bf16_f32(unsigned short h) {
    return __uint_as_float(((unsigned int)h) << 16);
}

// ---------------- Kernel 1: per-batch raw Gram G = X X^T (bf16 MFMA) + channel sums ----
// 1 workgroup per batch, 256 threads (4 waves). HBM-bound: streams 2 MB/batch once.
__global__ __launch_bounds__(256, 1)
void k_gram(const float* __restrict__ x, float* __restrict__ gws, float* __restrict__ sxws) {
    __shared__ __align__(16) unsigned short xl[2][NCH * LDSK];  // double-buffered bf16 tile
    __shared__ float red[256];

    const int tid  = threadIdx.x;
    const int b    = blockIdx.x;
    const int lane = tid & 63;
    const int wv   = tid >> 6;       // wave id 0..3
    const int lrow8  = tid >> 5;     // 0..7 (load row group)
    const int lchunk = tid & 31;     // 0..31 (load column chunk)

    const float* xb = x + (size_t)b * ((size_t)NCH * NT);

    f4_t acc[2][8];
    #pragma unroll
    for (int i = 0; i < 2; ++i)
        #pragma unroll
        for (int j = 0; j < 8; ++j)
            acc[i][j] = (f4_t){0.f, 0.f, 0.f, 0.f};

    float sxp = 0.f;
    float4 ld[16];

    // prologue: stage tile 0
    #pragma unroll
    for (int j = 0; j < 16; ++j) {
        const int r = j * 8 + lrow8;
        ld[j] = *(const float4*)(xb + (size_t)r * NT + lchunk * 4);
    }
    #pragma unroll
    for (int j = 0; j < 16; ++j) {
        const int r = j * 8 + lrow8;
        ushort4 h;
        h.x = f32_bf16(ld[j].x); h.y = f32_bf16(ld[j].y);
        h.z = f32_bf16(ld[j].z); h.w = f32_bf16(ld[j].w);
        *(ushort4*)&xl[0][r * LDSK + lchunk * 4] = h;
    }
    __syncthreads();

    for (int it = 0; it < NIT; ++it) {
        const int cur = it & 1;
        // issue next tile's global loads early (latency hides under MFMA)
        if (it + 1 < NIT) {
            const int t0 = (it + 1) * TT;
            #pragma unroll
            for (int j = 0; j < 16; ++j) {
                const int r = j * 8 + lrow8;
                ld[j] = *(const float4*)(xb + (size_t)r * NT + t0 + lchunk * 4);
            }
        }
        const unsigned short* bufc = xl[cur];
        {   // G += Xtile * Xtile^T : wave wv owns G rows 32wv..32wv+31, all 128 cols
            const int lrow = lane & 15;
            const int koff = (lane >> 4) * 8;
            #pragma unroll
            for (int ks = 0; ks < TT / 32; ++ks) {
                const int k0 = ks * 32 + koff;
                s8_t bf[8];
                #pragma unroll
                for (int cb = 0; cb < 8; ++cb)
                    bf[cb] = *(const s8_t*)&bufc[(cb * 16 + lrow) * LDSK + k0];
                #pragma unroll
                for (int i = 0; i < 2; ++i) {
                    const s8_t af = *(const s8_t*)&bufc[((wv * 2 + i) * 16 + lrow) * LDSK + k0];
                    #pragma unroll
                    for (int cb = 0; cb < 8; ++cb)
                        acc[i][cb] = __builtin_amdgcn_mfma_f32_16x16x32_bf16(af, bf[cb], acc[i][cb], 0, 0, 0);
                }
            }
        }
        {   // channel-sum partial: thread -> row tid>>1, half tid&1
            const unsigned short* rp = &bufc[(tid >> 1) * LDSK + (tid & 1) * 64];
            float s = 0.f;
            #pragma unroll
            for (int q8 = 0; q8 < 8; ++q8) {
                s8_t v = *(const s8_t*)&rp[q8 * 8];
                #pragma unroll
                for (int e = 0; e < 8; ++e)
                    s += bf16_f32((unsigned short)v[e]);
            }
            sxp += s;
        }
        // convert + stage next tile into the other buffer
        if (it + 1 < NIT) {
            #pragma unroll
            for (int j = 0; j < 16; ++j) {
                const int r = j * 8 + lrow8;
                ushort4 h;
                h.x = f32_bf16(ld[j].x); h.y = f32_bf16(ld[j].y);
                h.z = f32_bf16(ld[j].z); h.w = f32_bf16(ld[j].w);
                *(ushort4*)&xl[cur ^ 1][r * LDSK + lchunk * 4] = h;
            }
        }
        __syncthreads();
    }

    // store G  (C/D layout: col = lane&15, row = (lane>>4)*4 + reg  [m89-verified])
    float* gb = gws + ((size_t)b << 14);
    const int lrow4 = (lane >> 4) * 4;
    const int lcol  = lane & 15;
    #pragma unroll
    for (int i = 0; i < 2; ++i) {
        const int rbase = (wv * 2 + i) * 16 + lrow4;
        #pragma unroll
        for (int cb = 0; cb < 8; ++cb) {
            const int col = cb * 16 + lcol;
            #pragma unroll
            for (int reg = 0; reg < 4; ++reg)
                gb[(size_t)(rbase + reg) * NCH + col] = acc[i][cb][reg];
        }
    }
    red[tid] = sxp;
    __syncthreads();
    if (tid < NCH)
        sxws[b * NCH + tid] = red[2 * tid] + red[2 * tid + 1];
}

// ---------------- Kernel 2: cov build + matrix log via Chebyshev-Clenshaw + triu vec ----
// 1 workgroup per batch, 256 threads. VALU-bound 64x64 f32 matmuls.
__global__ __launch_bounds__(256, 1)
void k_logm(const float* __restrict__ gws, const float* __restrict__ sxws,
            const float* __restrict__ wmat, float* __restrict__ out) {
    __shared__ __align__(16) float lds[33032];
    float* sG   = lds;           // [128][128] Gram (dead after M1 phase)
    float* sC0  = lds;           // [64][64]  cov0   (reuses G region)
    float* sU   = lds;           // [64][64]  normalized arg (reuses C0)
    float* sB0  = lds + 4096;    // Clenshaw ping
    float* sB1  = lds + 8192;    // Clenshaw pong
    float* sA   = lds + 12288;   // [64][64]  shrunk cov
    float* sWt  = lds + 16384;   // [128][64] W transposed
    float* sM1t = lds + 24576;   // [128][64] (W*G) transposed
    float* ssx  = lds + 32768;   // [128]
    float* sp   = lds + 32896;   // [64]  p = W*sx
    float* sred = lds + 32960;   // [64]
    float* sscal= lds + 33024;   // scalars

    const int tid = threadIdx.x;
    const int b   = blockIdx.x;

    for (int i = tid; i < NF * NCH; i += 256) {   // W^T (W is L2-hot, 32 KB)
        const int k = i >> 6, f = i & 63;
        sWt[i] = wmat[f * NCH + k];
    }
    if (tid < NCH) ssx[tid] = sxws[b * NCH + tid];
    {
        const float* gb = gws + ((size_t)b << 14);
        for (int i = tid; i < NCH * NCH; i += 256) sG[i] = gb[i];
    }
    __syncthreads();

    // M1 = W*G (64x128), stored transposed. Thread block: 4 f-rows x 8 c-cols.
    {
        const int f0 = (tid >> 4) * 4, c0 = (tid & 15) * 8;
        float a[4][8];
        #pragma unroll
        for (int i = 0; i < 4; ++i)
            #pragma unroll
            for (int j = 0; j < 8; ++j) a[i][j] = 0.f;
        for (int k = 0; k < NCH; ++k) {
            const float4 wv4 = *(const float4*)&sWt[k * 64 + f0];
            const float4 gA  = *(const float4*)&sG[k * NCH + c0];
            const float4 gB  = *(const float4*)&sG[k * NCH + c0 + 4];
            const float wa[4] = {wv4.x, wv4.y, wv4.z, wv4.w};
            const float ga[8] = {gA.x, gA.y, gA.z, gA.w, gB.x, gB.y, gB.z, gB.w};
            #pragma unroll
            for (int i = 0; i < 4; ++i)
                #pragma unroll
                for (int j = 0; j < 8; ++j)
                    a[i][j] = fmaf(wa[i], ga[j], a[i][j]);
        }
        #pragma unroll
        for (int j = 0; j < 8; ++j) {
            float4 v; v.x = a[0][j]; v.y = a[1][j]; v.z = a[2][j]; v.w = a[3][j];
            *(float4*)&sM1t[(c0 + j) * 64 + f0] = v;
        }
    }
    if (tid < NF) {   // p = W * sx
        float s = 0.f;
        for (int k = 0; k < NCH; ++k) s = fmaf(sWt[k * 64 + tid], ssx[k], s);
        sp[tid] = s;
    }
    __syncthreads();

    // C0 = (M1*W^T - p p^T / T) / (T-1)
    {
        const int f0 = (tid >> 4) * 4, g0 = (tid & 15) * 4;
        float a[4][4];
        #pragma unroll
        for (int i = 0; i < 4; ++i)
            #pragma unroll
            for (int j = 0; j < 4; ++j) a[i][j] = 0.f;
        for (int k = 0; k < NCH; ++k) {
            const float4 mv = *(const float4*)&sM1t[k * 64 + f0];
            const float4 wv4 = *(const float4*)&sWt[k * 64 + g0];
            const float ma[4] = {mv.x, mv.y, mv.z, mv.w};
            const float wa[4] = {wv4.x, wv4.y, wv4.z, wv4.w};
            #pragma unroll
            for (int i = 0; i < 4; ++i)
                #pragma unroll
                for (int j = 0; j < 4; ++j)
                    a[i][j] = fmaf(ma[i], wa[j], a[i][j]);
        }
        const float i4096 = 1.f / 4096.f, i4095 = 1.f / 4095.f;
        #pragma unroll
        for (int i = 0; i < 4; ++i)
            #pragma unroll
            for (int j = 0; j < 4; ++j)
                sC0[(f0 + i) * 64 + (g0 + j)] =
                    (a[i][j] - sp[f0 + i] * sp[g0 + j] * i4096) * i4095;
    }
    __syncthreads();

    if (tid == 0) {                        // mu = trace/64
        float s = 0.f;
        for (int i = 0; i < 64; ++i) s += sC0[i * 65];
        sscal[0] = s * (1.f / 64.f);
    }
    __syncthreads();

    const float mu = sscal[0];
    const float dshift = 0.1f * mu + 1e-4f;   // == guaranteed lambda_min lower bound
    for (int i = tid; i < 4096; i += 256) {   // A = 0.45(C0+C0^T) + (0.1mu+eps) I
        const int r = i >> 6, c = i & 63;
        float v = 0.45f * (sC0[r * 64 + c] + sC0[c * 64 + r]);
        if (r == c) v += dshift;
        sA[i] = v;
    }
    __syncthreads();

    if (tid < 64) {                        // Gershgorin: column abs-sums (A symmetric)
        float s = 0.f;
        for (int j = 0; j < 64; ++j) s += fabsf(sA[j * 64 + tid]);
        sred[tid] = s;
    }
    __syncthreads();
    if (tid == 0) {
        float hi = 0.f;
        for (int i = 0; i < 64; ++i) hi = fmaxf(hi, sred[i]);
        const float lo = dshift;
        hi = fmaxf(hi, lo * 1.02f);
        float wsc = (hi - lo) / (hi + lo);
        wsc = fminf(fmaxf(wsc, 1e-6f), 0.999999f);
        const float zz = fmaxf((1.f - sqrtf(fmaxf(1.f - wsc * wsc, 1e-12f))) / wsc, 1e-12f);
        const float mc = 0.5f * (hi + lo);
        sscal[1] = mc;
        sscal[2] = wsc;
        sscal[3] = zz;
        sscal[4] = logf(mc) - log1pf(zz * zz);  // c0 of the Chebyshev series of log
    }
    __syncthreads();

    {   // U = (A/mc - I)/wsc, spectrum in [-1,1]
        const float mc = sscal[1], wsc = sscal[2];
        const float inv_mw = 1.f / (mc * wsc);
        const float inv_w  = 1.f / wsc;
        for (int i = tid; i < 4096; i += 256) {
            const int r = i >> 6, c = i & 63;
            float v = sA[i] * inv_mw;
            if (r == c) v -= inv_w;
            sU[i] = v;
        }
    }
    __syncthreads();

    // Matrix Clenshaw: log(x) = c0 + sum_{k=1..D} 2(-1)^{k+1} z^k/k * T_k(u)
    const int f0 = (tid >> 4) * 4, g0 = (tid & 15) * 4;
    const float zc  = sscal[3];
    const float l2z = log2f(zc);
    float rP[4][4], rP2[4][4];
    {
        const float cd = 2.f * ((CHEB_D & 1) ? 1.f : -1.f) *
                         exp2f((float)CHEB_D * l2z) / (float)CHEB_D;
        #pragma unroll
        for (int i = 0; i < 4; ++i)
            #pragma unroll
            for (int j = 0; j < 4; ++j) {
                rP[i][j]  = (f0 + i == g0 + j) ? cd : 0.f;
                rP2[i][j] = 0.f;
            }
        #pragma unroll
        for (int i = 0; i < 4; ++i) {
            float4 v; v.x = rP[i][0]; v.y = rP[i][1]; v.z = rP[i][2]; v.w = rP[i][3];
            *(float4*)&sB0[(f0 + i) * 64 + g0] = v;
        }
    }
    __syncthreads();

    float* bcur = sB0;
    float* bnxt = sB1;
    for (int k = CHEB_D - 1; k >= 1; --k) {
        const float ck = 2.f * ((k & 1) ? 1.f : -1.f) * exp2f((float)k * l2z) / (float)k;
        float a[4][4];
        #pragma unroll
        for (int i = 0; i < 4; ++i)
            #pragma unroll
            for (int j = 0; j < 4; ++j) a[i][j] = 0.f;
        for (int kk = 0; kk < 64; ++kk) {   // (U*B)[r][c] = sum_k U[k][r] B[k][c] (U symm)
            const float4 uv = *(const float4*)&sU[kk * 64 + f0];
            const float4 bv = *(const float4*)&bcur[kk * 64 + g0];
            const float ua[4] = {uv.x, uv.y, uv.z, uv.w};
            const float ba[4] = {bv.x, bv.y, bv.z, bv.w};
            #pragma unroll
            for (int i = 0; i < 4; ++i)
                #pragma unroll
                for (int j = 0; j < 4; ++j)
                    a[i][j] = fmaf(ua[i], ba[j], a[i][j]);
        }
        #pragma unroll
        for (int i = 0; i < 4; ++i)
            #pragma unroll
            for (int j = 0; j < 4; ++j) {
                const float v = 2.f * a[i][j] - rP2[i][j] + ((f0 + i == g0 + j) ? ck : 0.f);
                rP2[i][j] = rP[i][j];
                rP[i][j]  = v;
            }
        #pragma unroll
        for (int i = 0; i < 4; ++i) {
            float4 v; v.x = rP[i][0]; v.y = rP[i][1]; v.z = rP[i][2]; v.w = rP[i][3];
            *(float4*)&bnxt[(f0 + i) * 64 + g0] = v;
        }
        float* t = bcur; bcur = bnxt; bnxt = t;
        __syncthreads();
    }
    {   // final: F = c0 I + U*B1 - B2
        const float c0c = sscal[4];
        float a[4][4];
        #pragma unroll
        for (int i = 0; i < 4; ++i)
            #pragma unroll
            for (int j = 0; j < 4; ++j) a[i][j] = 0.f;
        for (int kk = 0; kk < 64; ++kk) {
            const float4 uv = *(const float4*)&sU[kk * 64 + f0];
            const float4 bv = *(const float4*)&bcur[kk * 64 + g0];
            const float ua[4] = {uv.x, uv.y, uv.z, uv.w};
            const float ba[4] = {bv.x, bv.y, bv.z, bv.w};
            #pragma unroll
            for (int i = 0; i < 4; ++i)
                #pragma unroll
                for (int j = 0; j < 4; ++j)
                    a[i][j] = fmaf(ua[i], ba[j], a[i][j]);
        }
        #pragma unroll
        for (int i = 0; i < 4; ++i) {
            float4 v;
            float vv[4];
            #pragma unroll
            for (int j = 0; j < 4; ++j)
                vv[j] = ((f0 + i == g0 + j) ? c0c : 0.f) + a[i][j] - rP2[i][j];
            v.x = vv[0]; v.y = vv[1]; v.z = vv[2]; v.w = vv[3];
            *(float4*)&bnxt[(f0 + i) * 64 + g0] = v;
        }
    }
    __syncthreads();
    const float* sF = bnxt;

    // symmetrize + triu vectorization with sqrt(2) off-diagonal scaling
    float* ob = out + (size_t)b * 2080;
    for (int idx = tid; idx < 2080; idx += 256) {
        const double disc = 16641.0 - 8.0 * (double)idx;
        const int i = (int)((129.0 - sqrt(disc)) * 0.5);
        const int Si = i * 64 - (i * (i - 1)) / 2;
        const int j = i + (idx - Si);
        float v = 0.5f * (sF[i * 64 + j] + sF[j * 64 + i]);
        if (i != j) v *= 1.4142135623730951f;
        ob[idx] = v;
    }
}

extern "C" void kernel_launch(void* const* d_in, const int* in_sizes, int n_in,
                              void* d_out, int out_size, void* d_ws, size_t ws_size,
                              hipStream_t stream) {
    const float* x    = (const float*)d_in[0];
    const float* wmat = (const float*)d_in[1];
    float* outp = (float*)d_out;
    float* gws  = (float*)d_ws;                               // 256*128*128 f32 = 16 MB
    float* sxws = gws + (size_t)NBATCH * NCH * NCH;           // 256*128 f32
    k_gram<<<dim3(NBATCH), dim3(256), 0, stream>>>(x, gws, sxws);
    k_logm<<<dim3(NBATCH), dim3(256), 0, stream>>>(gws, sxws, wmat, outp);
}